// Round 7
// baseline (244.548 us; speedup 1.0000x reference)
//
#include <hip/hip_runtime.h>
#include <hip/hip_bf16.h>

// MHA: B=4 S=1024 D=1024 H=16 depth=64. fp32 in/out; bf16 MFMA internally.

typedef __bf16 bf16x8 __attribute__((ext_vector_type(8)));
typedef __bf16 bf16x4 __attribute__((ext_vector_type(4)));
typedef float  f32x4  __attribute__((ext_vector_type(4)));
typedef float  f32x16 __attribute__((ext_vector_type(16)));

typedef const __attribute__((address_space(1))) void* gptr_t;
typedef __attribute__((address_space(3))) void* lptr_t;

#define MFMA16(a, b, c) __builtin_amdgcn_mfma_f32_16x16x32_bf16((a), (b), (c), 0, 0, 0)
#define MFMA32(a, b, c) __builtin_amdgcn_mfma_f32_32x32x16_bf16((a), (b), (c), 0, 0, 0)

__device__ __forceinline__ void gload_lds16(const void* g, void* l) {
  __builtin_amdgcn_global_load_lds((gptr_t)g, (lptr_t)l, 16, 0, 0);
}

__device__ __forceinline__ unsigned pack2(float a, float b) {
  union { __bf16 h[2]; unsigned u; } x;
  x.h[0] = (__bf16)a; x.h[1] = (__bf16)b; return x.u;
}

__device__ __forceinline__ bf16x8 mkfrag(unsigned a, unsigned b, unsigned c, unsigned d) {
  union { unsigned w[4]; bf16x8 v; } x;
  x.w[0] = a; x.w[1] = b; x.w[2] = c; x.w[3] = d; return x.v;
}

// ---------------- mask dtype detection + bit packing ----------------
__global__ void detect_mask(const unsigned char* m, int* flag) {
  __shared__ int s1[4], s23[4];
  int tid = threadIdx.x;
  uint4 v = ((const uint4*)m)[tid];
  unsigned x0 = v.x, x1 = v.y, x2 = v.z, x3 = v.w;
  unsigned c1  = (x0 & 0x0000ff00u) | (x1 & 0x0000ff00u) | (x2 & 0x0000ff00u) | (x3 & 0x0000ff00u);
  unsigned c23 = (x0 & 0xffff0000u) | (x1 & 0xffff0000u) | (x2 & 0xffff0000u) | (x3 & 0xffff0000u);
  unsigned long long b1 = __ballot(c1 != 0), b23 = __ballot(c23 != 0);
  if ((tid & 63) == 0) { s1[tid >> 6] = (b1 != 0); s23[tid >> 6] = (b23 != 0); }
  __syncthreads();
  if (tid == 0) {
    int a1 = s1[0] | s1[1] | s1[2] | s1[3];
    int a23 = s23[0] | s23[1] | s23[2] | s23[3];
    *flag = a1 ? 1 : (a23 ? 2 : 0);
  }
}

__global__ void pack_mask(const void* m, const int* flag, unsigned int* out) {
  size_t i = (size_t)blockIdx.x * 256 + threadIdx.x;
  int f = *flag;
  bool v;
  if (f == 1)      v = ((const unsigned char*)m)[i] != 0;
  else if (f == 2) v = ((const float*)m)[i] != 0.0f;
  else             v = ((const int*)m)[i] != 0;
  unsigned long long bal = __ballot(v);
  int lane = threadIdx.x & 63;
  if ((lane & 31) == 0) out[i >> 5] = (unsigned int)(bal >> (lane & 32));
}

// ---------------- fp32 -> bf16 convert, all 7 tensors in one dispatch ----------------
__global__ void cvt_all(const float* q, const float* k, const float* v,
                        const float* w0, const float* w1, const float* w2, const float* w3,
                        __bf16* oq, __bf16* ok, __bf16* ov,
                        __bf16* o0, __bf16* o1, __bf16* o2, __bf16* o3) {
  int bid = blockIdx.x;
  const float* in; __bf16* out; int sub;
  if (bid < 12288) {
    int w = bid >> 12; sub = bid & 4095;
    in = w == 0 ? q : w == 1 ? k : v;
    out = w == 0 ? oq : w == 1 ? ok : ov;
  } else {
    int w = (bid - 12288) >> 10; sub = (bid - 12288) & 1023;
    in = w == 0 ? w0 : w == 1 ? w1 : w == 2 ? w2 : w3;
    out = w == 0 ? o0 : w == 1 ? o1 : w == 2 ? o2 : o3;
  }
  size_t i = (size_t)sub * 256 + threadIdx.x;
  float4 vv = ((const float4*)in)[i];
  bf16x4 o; o[0] = (__bf16)vv.x; o[1] = (__bf16)vv.y; o[2] = (__bf16)vv.z; o[3] = (__bf16)vv.w;
  ((bf16x4*)out)[i] = o;
}

// ---------------- fused QKV projection GEMM: 256x256, 32x32x16 MFMA, k-split phases ----------------
// BM=BN=256, BK=64, 512 threads (8 waves, 2M x 4N), per-wave 128x64 out as 4x2 of 32x32.
// Per K-tile: burst-stage next tile's 8 loads at boundary + vmcnt(8) (loads were
// issued a full tile earlier -> wait nearly free), barrier, then 2 k-split phases
// (each reads its frags exactly once: 12 ds_read_b128, 16 MFMA32). r6's quadrant
// phases re-read A/B (48 reads/tile) and were LDS-BW-bound; k-split = 24 reads.
__global__ __launch_bounds__(512, 2)
void gemm_qkv8(const __bf16* __restrict__ qb, const __bf16* __restrict__ kb,
               const __bf16* __restrict__ vb,
               const __bf16* __restrict__ wq, const __bf16* __restrict__ wk,
               const __bf16* __restrict__ wv,
               const float* __restrict__ bq, const float* __restrict__ bk,
               const float* __restrict__ bv,
               __bf16* __restrict__ Qp, __bf16* __restrict__ Kp, __bf16* __restrict__ Vt) {
  __shared__ __bf16 As[2][256 * 64];   // 32 KB per buf
  __shared__ __bf16 Bs[2][256 * 64];   // total 128 KB
  const int bm = blockIdx.x;           // 0..15
  const int bnall = blockIdx.y;        // 0..11
  const int which = bnall >> 2;        // 0:Q 1:K 2:V
  const int bnl = bnall & 3;
  const __bf16* A = which == 0 ? qb : which == 1 ? kb : vb;
  const __bf16* W = which == 0 ? wq : which == 1 ? wk : wv;
  const float* bias = which == 0 ? bq : which == 1 ? bk : bv;

  const int tid = threadIdx.x, wave = tid >> 6, lane = tid & 63;
  const int wr = wave >> 2, wc = wave & 3;          // 2M x 4N wave grid
  const int lo5 = lane & 31, hi = lane >> 5;
  const int srow = tid >> 3;                        // staging row 0..63
  const int sgw = ((tid & 7) ^ (srow & 7)) << 3;    // pre-swizzled source granule
  f32x16 acc[4][2] = {};

  // half hp: 0=A rows 0-127, 1=A rows 128-255, 2=B rows 0-127, 3=B rows 128-255
  // wave w stages srow = w*8 + (lane>>3); LDS dest per-wave base (r6 fix)
#define STAGE_HALF(bb, u, hp)                                                   \
  {                                                                             \
    _Pragma("unroll")                                                           \
    for (int i_ = 0; i_ < 2; ++i_) {                                            \
      int row_ = ((hp) & 1) * 128 + i_ * 64 + srow;                             \
      if ((hp) < 2)                                                             \
        gload_lds16(A + (size_t)(bm * 256 + row_) * 1024 + (u) * 64 + sgw,      \
                    &As[bb][(((hp) & 1) * 128 + i_ * 64 + wave * 8) * 64]);     \
      else                                                                      \
        gload_lds16(W + (size_t)(bnl * 256 + row_) * 1024 + (u) * 64 + sgw,     \
                    &Bs[bb][(((hp) & 1) * 128 + i_ * 64 + wave * 8) * 64]);     \
    }                                                                           \
  }

  // k-split phase kh in {0,1}: k-slices ks = kh*2+kk, k = ks*16 + hi*8 + j
#define PHASEK(curb, kh)                                                        \
  {                                                                             \
    bf16x8 af_[4][2], bf_[2][2];                                                \
    _Pragma("unroll")                                                           \
    for (int mi_ = 0; mi_ < 4; ++mi_) {                                         \
      int row_ = wr * 128 + mi_ * 32 + lo5;                                     \
      _Pragma("unroll")                                                         \
      for (int kk_ = 0; kk_ < 2; ++kk_)                                         \
        af_[mi_][kk_] = *(const bf16x8*)(&As[curb][row_ * 64 +                  \
            (((((kh) * 2 + kk_) * 2 + hi) ^ (row_ & 7)) << 3)]);                \
    }                                                                           \
    _Pragma("unroll")                                                           \
    for (int ni_ = 0; ni_ < 2; ++ni_) {                                         \
      int row_ = wc * 64 + ni_ * 32 + lo5;                                      \
      _Pragma("unroll")                                                         \
      for (int kk_ = 0; kk_ < 2; ++kk_)                                         \
        bf_[ni_][kk_] = *(const bf16x8*)(&Bs[curb][row_ * 64 +                  \
            (((((kh) * 2 + kk_) * 2 + hi) ^ (row_ & 7)) << 3)]);                \
    }                                                                           \
    __builtin_amdgcn_s_barrier();                                               \
    __builtin_amdgcn_sched_barrier(0);                                          \
    __builtin_amdgcn_s_setprio(1);                                              \
    _Pragma("unroll")                                                           \
    for (int kk_ = 0; kk_ < 2; ++kk_)                                           \
      _Pragma("unroll")                                                         \
      for (int mi_ = 0; mi_ < 4; ++mi_)                                         \
        _Pragma("unroll")                                                       \
        for (int ni_ = 0; ni_ < 2; ++ni_)                                       \
          acc[mi_][ni_] = MFMA32(af_[mi_][kk_], bf_[ni_][kk_], acc[mi_][ni_]);  \
    __builtin_amdgcn_s_setprio(0);                                              \
    __builtin_amdgcn_s_barrier();                                               \
    __builtin_amdgcn_sched_barrier(0);                                          \
  }

  // prologue: stage K-tile 0
  STAGE_HALF(0, 0, 0); STAGE_HALF(0, 0, 1); STAGE_HALF(0, 0, 2); STAGE_HALF(0, 0, 3);
  int cur = 0;
#pragma unroll 1
  for (int u = 0; u < 16; ++u) {
    const int oth = cur ^ 1;
    if (u < 15) {
      STAGE_HALF(oth, u + 1, 0); STAGE_HALF(oth, u + 1, 1);
      STAGE_HALF(oth, u + 1, 2); STAGE_HALF(oth, u + 1, 3);
      asm volatile("s_waitcnt vmcnt(8)" ::: "memory");   // tile-u's 8 loads retired
    } else {
      asm volatile("s_waitcnt vmcnt(0)" ::: "memory");
    }
    __builtin_amdgcn_s_barrier();
    __builtin_amdgcn_sched_barrier(0);
    PHASEK(cur, 0);
    PHASEK(cur, 1);
    cur ^= 1;
  }

  // epilogue: 32x32 C layout col=lane&31, row=(r&3)+8*(r>>2)+4*hi
  const float osc = (which == 0) ? 0.18033688011112042f : 1.0f;  // fold 1/8*log2(e) into Q
  __bf16* Onat = which == 0 ? Qp : Kp;
#pragma unroll
  for (int mi = 0; mi < 4; ++mi) {
    int rowb0 = bm * 256 + wr * 128 + mi * 32;
#pragma unroll
    for (int ni = 0; ni < 2; ++ni) {
      int col = bnl * 256 + wc * 64 + ni * 32 + lo5;
      float bvv = bias[col];
      if (which < 2) {
#pragma unroll
        for (int r = 0; r < 16; ++r) {
          int rw = rowb0 + (r & 3) + 8 * (r >> 2) + 4 * hi;
          Onat[(size_t)rw * 1024 + col] = (__bf16)((acc[mi][ni][r] + bvv) * osc);
        }
      } else {
        int hh = col >> 6, d = col & 63;
        int bb2 = rowb0 >> 10;
#pragma unroll
        for (int q = 0; q < 4; ++q) {
          int s0 = (rowb0 & 1023) + 8 * q + 4 * hi;
          bf16x4 ov;
#pragma unroll
          for (int r = 0; r < 4; ++r) ov[r] = (__bf16)(acc[mi][ni][4 * q + r] + bvv);
          *(bf16x4*)(Vt + (((size_t)(bb2 * 16 + hh) * 64 + d) << 10) + s0) = ov;
        }
      }
    }
  }
#undef STAGE_HALF
#undef PHASEK
}

// ---------------- output projection GEMM (fp32 out): 128x128, 32x32x16, k-split ----------------
__global__ __launch_bounds__(256, 2)
void gemm_fc(const __bf16* __restrict__ A, const __bf16* __restrict__ W,
             const float* __restrict__ bias, float* __restrict__ C) {
  __shared__ __bf16 As[2][128 * 64];
  __shared__ __bf16 Bs[2][128 * 64];
  const int bm = blockIdx.x, bn = blockIdx.y;
  const int tid = threadIdx.x, wave = tid >> 6, lane = tid & 63;
  const int wr = wave >> 1, wc = wave & 1;
  const int lo5 = lane & 31, hi = lane >> 5;
  const int rl = lane >> 3, c8 = lane & 7;
  f32x16 acc[2][2] = {};

#define FC_STAGE(bb, kt)                                                              \
  {                                                                                   \
    _Pragma("unroll")                                                                 \
    for (int i = 0; i < 4; ++i) {                                                     \
      int row = wave * 32 + i * 8 + rl;                                               \
      int sw = (c8 ^ (row & 7)) << 3;                                                 \
      gload_lds16(A + (size_t)(bm * 128 + row) * 1024 + (kt) * 64 + sw,               \
                  &As[bb][(wave * 32 + i * 8) * 64]);                                 \
      gload_lds16(W + (size_t)(bn * 128 + row) * 1024 + (kt) * 64 + sw,               \
                  &Bs[bb][(wave * 32 + i * 8) * 64]);                                 \
    }                                                                                 \
  }

#define FPHASEK(curb, kh)                                                       \
  {                                                                             \
    bf16x8 af_[2][2], bf_[2][2];                                                \
    _Pragma("unroll")                                                           \
    for (int mi_ = 0; mi_ < 2; ++mi_) {                                         \
      int row_ = wr * 64 + mi_ * 32 + lo5;                                      \
      _Pragma("unroll")                                                         \
      for (int kk_ = 0; kk_ < 2; ++kk_)                                         \
        af_[mi_][kk_] = *(const bf16x8*)(&As[curb][row_ * 64 +                  \
            (((((kh) * 2 + kk_) * 2 + hi) ^ (row_ & 7)) << 3)]);                \
    }                                                                           \
    _Pragma("unroll")                                                           \
    for (int ni_ = 0; ni_ < 2; ++ni_) {                                         \
      int row_ = wc * 64 + ni_ * 32 + lo5;                                      \
      _Pragma("unroll")                                                         \
      for (int kk_ = 0; kk_ < 2; ++kk_)                                         \
        bf_[ni_][kk_] = *(const bf16x8*)(&Bs[curb][row_ * 64 +                  \
            (((((kh) * 2 + kk_) * 2 + hi) ^ (row_ & 7)) << 3)]);                \
    }                                                                           \
    __builtin_amdgcn_s_barrier();                                               \
    __builtin_amdgcn_sched_barrier(0);                                          \
    __builtin_amdgcn_s_setprio(1);                                              \
    _Pragma("unroll")                                                           \
    for (int kk_ = 0; kk_ < 2; ++kk_)                                           \
      _Pragma("unroll")                                                         \
      for (int mi_ = 0; mi_ < 2; ++mi_)                                         \
        _Pragma("unroll")                                                       \
        for (int ni_ = 0; ni_ < 2; ++ni_)                                       \
          acc[mi_][ni_] = MFMA32(af_[mi_][kk_], bf_[ni_][kk_], acc[mi_][ni_]);  \
    __builtin_amdgcn_s_setprio(0);                                              \
    __builtin_amdgcn_s_barrier();                                               \
    __builtin_amdgcn_sched_barrier(0);                                          \
  }

  FC_STAGE(0, 0);
  int buf = 0;
#pragma unroll 1
  for (int kt = 0; kt < 16; ++kt) {
    if (kt < 15) {
      FC_STAGE(buf ^ 1, kt + 1);
      asm volatile("s_waitcnt vmcnt(8)" ::: "memory");
    } else {
      asm volatile("s_waitcnt vmcnt(0)" ::: "memory");
    }
    __builtin_amdgcn_s_barrier();
    __builtin_amdgcn_sched_barrier(0);
    FPHASEK(buf, 0);
    FPHASEK(buf, 1);
    buf ^= 1;
  }

  const float* __restrict__ bp = bias;
#pragma unroll
  for (int mi = 0; mi < 2; ++mi) {
    int rowb0 = bm * 128 + wr * 64 + mi * 32;
#pragma unroll
    for (int ni = 0; ni < 2; ++ni) {
      int col = bn * 128 + wc * 64 + ni * 32 + lo5;
      float bvv = bp[col];
#pragma unroll
      for (int r = 0; r < 16; ++r) {
        int rw = rowb0 + (r & 3) + 8 * (r >> 2) + 4 * hi;
        C[(size_t)rw * 1024 + col] = acc[mi][ni][r] + bvv;
      }
    }
  }
#undef FC_STAGE
#undef FPHASEK
}

// ---------------- fused attention: LDS-staged K/V + in-register P ----------------
__global__ __launch_bounds__(256)
void attn32(const __bf16* __restrict__ Qp, const __bf16* __restrict__ Kp,
            const __bf16* __restrict__ Vt, const unsigned int* __restrict__ mp,
            __bf16* __restrict__ O) {
  __shared__ __bf16 Ks[2][64 * 64];
  __shared__ __bf16 Vs[2][64 * 64];
  const int tid = threadIdx.x, wave = tid >> 6, lane = tid & 63;
  const int lo5 = lane & 31, hi = lane >> 5;
  const int bx = blockIdx.x;
  const int qt = bx & 7, h = (bx >> 3) & 15, b = bx >> 7;
  const int qrow = qt * 128 + wave * 32 + lo5;

  const int srow = tid >> 3;
  const int sgx = ((tid & 7) ^ (srow & 7)) << 3;

#define ATTN_STAGE(bb, kt)                                                            \
  {                                                                                   \
    _Pragma("unroll")                                                                 \
    for (int i = 0; i < 2; ++i) {                                                     \
      gload_lds16(Kp + (size_t)(b * 1024 + (kt) * 64 + i * 32 + srow) * 1024          \
                     + h * 64 + sgx,                                                  \
                  &Ks[bb][i * 2048 + wave * 512]);                                    \
      gload_lds16(Vt + (size_t)((b * 16 + h) * 64 + i * 32 + srow) * 1024             \
                     + (kt) * 64 + sgx,                                               \
                  &Vs[bb][i * 2048 + wave * 512]);                                    \
    }                                                                                 \
  }

  bf16x8 qf[4];
  const __bf16* qb = Qp + ((size_t)(b * 1024 + qrow)) * 1024 + h * 64 + hi * 8;
#pragma unroll
  for (int m = 0; m < 4; ++m) qf[m] = *(const bf16x8*)(qb + m * 16);

  bf16x8 onesf;
#pragma unroll
  for (int i = 0; i < 8; ++i) onesf[i] = (__bf16)1.0f;

  f32x16 oacc0 = {}, oacc1 = {}, oaccD = {};
  const uint2* mrow = ((const uint2*)mp) + ((size_t)(b * 1024 + qrow)) * 16;
  const int x = lo5 & 7;

  ATTN_STAGE(0, 0);
  uint2 mwc = mrow[0];
  __syncthreads();
  int buf = 0;
  for (int kt = 0; kt < 16; ++kt) {
    if (kt < 15) ATTN_STAGE(buf ^ 1, kt + 1);
    uint2 mwn = mwc;
    if (kt < 15) mwn = mrow[kt + 1];
#pragma unroll
    for (int sub = 0; sub < 2; ++sub) {
      f32x16 s = {};
#pragma unroll
      for (int m = 0; m < 4; ++m) {
        bf16x8 kf = *(const bf16x8*)(&Ks[buf][(sub * 32 + lo5) * 64 + (((2 * m + hi) ^ x) << 3)]);
        s = MFMA32(kf, qf[m], s);
      }
      unsigned w32 = sub == 0 ? mwc.x : mwc.y;
      unsigned nw = ~(w32 >> (hi * 4));
      float p[16];
#pragma unroll
      for (int r = 0; r < 16; ++r) {
        float e = __builtin_amdgcn_exp2f(s[r]);
        unsigned keep = (unsigned)__builtin_amdgcn_sbfe((int)nw, (unsigned)((r & 3) + 8 * (r >> 2)), 1u);
        p[r] = __uint_as_float(__float_as_uint(e) & keep);
      }
      unsigned own[8];
#pragma unroll
      for (int u = 0; u < 4; ++u) {
        own[2 * u]     = pack2(p[4 * u],     p[4 * u + 1]);
        own[2 * u + 1] = pack2(p[4 * u + 2], p[4 * u + 3]);
      }
#pragma unroll
      for (int sf = 0; sf < 2; ++sf) {
        unsigned a0 = own[4 * sf + 0], b0 = own[4 * sf + 2];
        unsigned a1 = own[4 * sf + 1], b1 = own[4 * sf + 3];
        asm volatile("v_permlane32_swap_b32 %0, %1" : "+v"(a0), "+v"(b0));
        asm volatile("v_permlane32_swap_b32 %0, %1" : "+v"(a1), "+v"(b1));
        bf16x8 pa = mkfrag(a0, a1, b0, b1);
        int g = ((sub * 4 + sf * 2 + hi) ^ x) << 3;
        bf16x8 vf0 = *(const bf16x8*)(&Vs[buf][lo5 * 64 + g]);
        bf16x8 vf1 = *(const bf16x8*)(&Vs[buf][(lo5 + 32) * 64 + g]);
        oacc0 = MFMA32(pa, vf0, oacc0);
        oacc1 = MFMA32(pa, vf1, oacc1);
        oaccD = MFMA32(pa, onesf, oaccD);
      }
    }
    __syncthreads();
    buf ^= 1;
    mwc = mwn;
  }

  const size_t orow0 = (size_t)(b * 1024 + qt * 128 + wave * 32);
#pragma unroll
  for (int r = 0; r < 16; ++r) {
    int cr = (r & 3) + 8 * (r >> 2) + 4 * hi;
    float iv = __builtin_amdgcn_rcpf(oaccD[r]);
    __bf16* op = O + (orow0 + cr) * 1024 + h * 64 + lo5;
    op[0]  = (__bf16)(oacc0[r] * iv);
    op[32] = (__bf16)(oacc1[r] * iv);
  }
}

// ---------------- launch ----------------
extern "C" void kernel_launch(void* const* d_in, const int* in_sizes, int n_in,
                              void* d_out, int out_size, void* d_ws, size_t ws_size,
                              hipStream_t stream) {
  const float* query = (const float*)d_in[0];
  const float* key   = (const float*)d_in[1];
  const float* value = (const float*)d_in[2];
  const void*  mask  = d_in[3];
  const float* wq_w  = (const float*)d_in[4];
  const float* wq_b  = (const float*)d_in[5];
  const float* wk_w  = (const float*)d_in[6];
  const float* wk_b  = (const float*)d_in[7];
  const float* wv_w  = (const float*)d_in[8];
  const float* wv_b  = (const float*)d_in[9];
  const float* fc_w  = (const float*)d_in[10];
  const float* fc_b  = (const float*)d_in[11];

  char* ws = (char*)d_ws;
  __bf16* qb  = (__bf16*)ws;
  __bf16* kb  = qb  + 4194304;
  __bf16* vb  = kb  + 4194304;
  __bf16* wqb = vb  + 4194304;
  __bf16* wkb = wqb + 1048576;
  __bf16* wvb = wkb + 1048576;
  __bf16* fcb = wvb + 1048576;
  __bf16* Qp  = fcb + 1048576;
  __bf16* Kp  = Qp  + 4194304;
  __bf16* Vt  = Kp  + 4194304;        // V proj, per-head transposed [B,H,64,S]
  __bf16* Ob  = Vt  + 4194304;
  unsigned int* mpk = (unsigned int*)(Ob + 4194304);
  int* flag = (int*)(mpk + 131072);

  detect_mask<<<1, 256, 0, stream>>>((const unsigned char*)mask, flag);
  pack_mask<<<16384, 256, 0, stream>>>(mask, flag, mpk);
  cvt_all<<<16384, 256, 0, stream>>>(query, key, value, wq_w, wk_w, wv_w, fc_w,
                                     qb, kb, vb, wqb, wkb, wvb, fcb);
  dim3 g1(16, 12);
  gemm_qkv8<<<g1, 512, 0, stream>>>(qb, kb, vb, wqb, wkb, wvb, wq_b, wk_b, wv_b, Qp, Kp, Vt);
  attn32<<<512, 256, 0, stream>>>(Qp, Kp, Vt, mpk, Ob);
  dim3 g2(32, 8);
  gemm_fc<<<g2, 256, 0, stream>>>(Ob, fcb, fc_b, (float*)d_out);
}

// Round 10
// 226.221 us; speedup vs baseline: 1.0810x; 1.0810x over previous
//
#include <hip/hip_runtime.h>
#include <hip/hip_bf16.h>

// MHA: B=4 S=1024 D=1024 H=16 depth=64. fp32 in/out; bf16 MFMA internally.

typedef __bf16 bf16x8 __attribute__((ext_vector_type(8)));
typedef __bf16 bf16x4 __attribute__((ext_vector_type(4)));
typedef float  f32x4  __attribute__((ext_vector_type(4)));
typedef float  f32x16 __attribute__((ext_vector_type(16)));

typedef const __attribute__((address_space(1))) void* gptr_t;
typedef __attribute__((address_space(3))) void* lptr_t;

#define MFMA16(a, b, c) __builtin_amdgcn_mfma_f32_16x16x32_bf16((a), (b), (c), 0, 0, 0)
#define MFMA32(a, b, c) __builtin_amdgcn_mfma_f32_32x32x16_bf16((a), (b), (c), 0, 0, 0)

__device__ __forceinline__ void gload_lds16(const void* g, void* l) {
  __builtin_amdgcn_global_load_lds((gptr_t)g, (lptr_t)l, 16, 0, 0);
}

__device__ __forceinline__ unsigned pack2(float a, float b) {
  union { __bf16 h[2]; unsigned u; } x;
  x.h[0] = (__bf16)a; x.h[1] = (__bf16)b; return x.u;
}

__device__ __forceinline__ bf16x8 mkfrag(unsigned a, unsigned b, unsigned c, unsigned d) {
  union { unsigned w[4]; bf16x8 v; } x;
  x.w[0] = a; x.w[1] = b; x.w[2] = c; x.w[3] = d; return x.v;
}

// ---------------- mask dtype detection + bit packing (r7-proven) ----------------
__global__ void detect_mask(const unsigned char* m, int* flag) {
  __shared__ int s1[4], s23[4];
  int tid = threadIdx.x;
  uint4 v = ((const uint4*)m)[tid];
  unsigned x0 = v.x, x1 = v.y, x2 = v.z, x3 = v.w;
  unsigned c1  = (x0 & 0x0000ff00u) | (x1 & 0x0000ff00u) | (x2 & 0x0000ff00u) | (x3 & 0x0000ff00u);
  unsigned c23 = (x0 & 0xffff0000u) | (x1 & 0xffff0000u) | (x2 & 0xffff0000u) | (x3 & 0xffff0000u);
  unsigned long long b1 = __ballot(c1 != 0), b23 = __ballot(c23 != 0);
  if ((tid & 63) == 0) { s1[tid >> 6] = (b1 != 0); s23[tid >> 6] = (b23 != 0); }
  __syncthreads();
  if (tid == 0) {
    int a1 = s1[0] | s1[1] | s1[2] | s1[3];
    int a23 = s23[0] | s23[1] | s23[2] | s23[3];
    *flag = a1 ? 1 : (a23 ? 2 : 0);
  }
}

__global__ void pack_mask(const void* m, const int* flag, unsigned int* out) {
  size_t i = (size_t)blockIdx.x * 256 + threadIdx.x;
  int f = *flag;
  bool v;
  if (f == 1)      v = ((const unsigned char*)m)[i] != 0;
  else if (f == 2) v = ((const float*)m)[i] != 0.0f;
  else             v = ((const int*)m)[i] != 0;
  unsigned long long bal = __ballot(v);
  int lane = threadIdx.x & 63;
  if ((lane & 31) == 0) out[i >> 5] = (unsigned int)(bal >> (lane & 32));
}

// ---------------- fp32 -> bf16 convert, all 7 tensors in one dispatch (r7-proven) ----------------
__global__ void cvt_all(const float* q, const float* k, const float* v,
                        const float* w0, const float* w1, const float* w2, const float* w3,
                        __bf16* oq, __bf16* ok, __bf16* ov,
                        __bf16* o0, __bf16* o1, __bf16* o2, __bf16* o3) {
  int bid = blockIdx.x;
  const float* in; __bf16* out; int sub;
  if (bid < 12288) {
    int w = bid >> 12; sub = bid & 4095;
    in = w == 0 ? q : w == 1 ? k : v;
    out = w == 0 ? oq : w == 1 ? ok : ov;
  } else {
    int w = (bid - 12288) >> 10; sub = (bid - 12288) & 1023;
    in = w == 0 ? w0 : w == 1 ? w1 : w == 2 ? w2 : w3;
    out = w == 0 ? o0 : w == 1 ? o1 : w == 2 ? o2 : o3;
  }
  size_t i = (size_t)sub * 256 + threadIdx.x;
  float4 vv = ((const float4*)in)[i];
  bf16x4 o; o[0] = (__bf16)vv.x; o[1] = (__bf16)vv.y; o[2] = (__bf16)vv.z; o[3] = (__bf16)vv.w;
  ((bf16x4*)out)[i] = o;
}

// ---------------- fused QKV projection GEMM: 128x128, MFMA16, 2-tile-deep pipeline ----------------
// TEST SUBJECT this round. 4 waves (2x2), r4-proven frag algebra (0 bank conflicts).
// Tiles 0,1 prestaged; per iter: vmcnt(8) (waits loads issued TWO tiles ago), barrier,
// frag reads, lgkm0+barrier, stage kt+2 into just-read buffer (overlaps MFMA), MFMA.
__global__ __launch_bounds__(256, 2)
void gemm_qkv2(const __bf16* __restrict__ qb, const __bf16* __restrict__ kb,
               const __bf16* __restrict__ vb,
               const __bf16* __restrict__ wq, const __bf16* __restrict__ wk,
               const __bf16* __restrict__ wv,
               const float* __restrict__ bq, const float* __restrict__ bk,
               const float* __restrict__ bv,
               __bf16* __restrict__ Qp, __bf16* __restrict__ Kp, __bf16* __restrict__ Vt) {
  __shared__ __bf16 As[2][128 * 64];
  __shared__ __bf16 Bs[2][128 * 64];
  const int bm = blockIdx.x;
  const int bnall = blockIdx.y;
  const int which = bnall >> 3;
  const int bn = bnall & 7;
  const __bf16* A = which == 0 ? qb : which == 1 ? kb : vb;
  const __bf16* W = which == 0 ? wq : which == 1 ? wk : wv;
  const float* bias = which == 0 ? bq : which == 1 ? bk : bv;

  const int tid = threadIdx.x, wave = tid >> 6, lane = tid & 63;
  const int wr = wave >> 1, wc = wave & 1;
  const int l15 = lane & 15, l4 = lane >> 4;
  const int rl = lane >> 3, c8 = lane & 7;
  f32x4 acc[4][4] = {};

#define QKV_STAGE(bb, kt)                                                             \
  {                                                                                   \
    _Pragma("unroll")                                                                 \
    for (int i_ = 0; i_ < 4; ++i_) {                                                  \
      int row_ = wave * 32 + i_ * 8 + rl;                                             \
      int sw_ = (c8 ^ (row_ & 7)) << 3;                                               \
      gload_lds16(A + (size_t)(bm * 128 + row_) * 1024 + (kt) * 64 + sw_,             \
                  &As[bb][(wave * 32 + i_ * 8) * 64]);                                \
      gload_lds16(W + (size_t)(bn * 128 + row_) * 1024 + (kt) * 64 + sw_,             \
                  &Bs[bb][(wave * 32 + i_ * 8) * 64]);                                \
    }                                                                                 \
  }

  QKV_STAGE(0, 0);
  QKV_STAGE(1, 1);
  int cur = 0;
#pragma unroll 1
  for (int kt = 0; kt < 16; ++kt) {
    if (kt < 15) asm volatile("s_waitcnt vmcnt(8)" ::: "memory");
    else         asm volatile("s_waitcnt vmcnt(0)" ::: "memory");
    __builtin_amdgcn_s_barrier();           // buf[cur] filled & visible
    __builtin_amdgcn_sched_barrier(0);
    bf16x8 af[4][2], bfr[4][2];
#pragma unroll
    for (int mi = 0; mi < 4; ++mi) {
      int row = wr * 64 + mi * 16 + l15;
#pragma unroll
      for (int k32 = 0; k32 < 2; ++k32)
        af[mi][k32] = *(const bf16x8*)(&As[cur][row * 64 + (((k32 * 4 + l4) ^ (row & 7)) << 3)]);
    }
#pragma unroll
    for (int ni = 0; ni < 4; ++ni) {
      int row = wc * 64 + ni * 16 + l15;
#pragma unroll
      for (int k32 = 0; k32 < 2; ++k32)
        bfr[ni][k32] = *(const bf16x8*)(&Bs[cur][row * 64 + (((k32 * 4 + l4) ^ (row & 7)) << 3)]);
    }
    asm volatile("s_waitcnt lgkmcnt(0)" ::: "memory");
    __builtin_amdgcn_sched_barrier(0);
    __builtin_amdgcn_s_barrier();           // all waves done reading buf[cur]
    __builtin_amdgcn_sched_barrier(0);
    if (kt < 14) QKV_STAGE(cur, kt + 2);    // overwrite cur; overlaps MFMA below
    __builtin_amdgcn_s_setprio(1);
#pragma unroll
    for (int k32 = 0; k32 < 2; ++k32)
#pragma unroll
      for (int mi = 0; mi < 4; ++mi)
#pragma unroll
        for (int ni = 0; ni < 4; ++ni)
          acc[mi][ni] = MFMA16(af[mi][k32], bfr[ni][k32], acc[mi][ni]);
    __builtin_amdgcn_s_setprio(0);
    cur ^= 1;
  }

  // epilogue: C frag layout col=lane&15, row=(lane>>4)*4+reg (r4-proven)
  const int r0 = l4 * 4, cl = l15;
  const float osc = (which == 0) ? 0.18033688011112042f : 1.0f;  // fold 1/8*log2(e) into Q
  __bf16* Onat = which == 0 ? Qp : Kp;
#pragma unroll
  for (int ni = 0; ni < 4; ++ni) {
    int col = bn * 128 + wc * 64 + ni * 16 + cl;
    float bvv = bias[col];
#pragma unroll
    for (int mi = 0; mi < 4; ++mi) {
      int rowb = bm * 128 + wr * 64 + mi * 16 + r0;
      if (which < 2) {
#pragma unroll
        for (int r = 0; r < 4; ++r)
          Onat[(size_t)(rowb + r) * 1024 + col] = (__bf16)((acc[mi][ni][r] + bvv) * osc);
      } else {
        int bb = rowb >> 10, s0 = rowb & 1023, hh = col >> 6, d = col & 63;
        bf16x4 ov;
#pragma unroll
        for (int r = 0; r < 4; ++r) ov[r] = (__bf16)(acc[mi][ni][r] + bvv);
        *(bf16x4*)(Vt + (((size_t)(bb * 16 + hh) * 64 + d) << 10) + s0) = ov;
      }
    }
  }
#undef QKV_STAGE
}

// ---------------- output projection GEMM (fp32 out): same 2-deep pipeline ----------------
__global__ __launch_bounds__(256, 2)
void gemm_fc(const __bf16* __restrict__ A, const __bf16* __restrict__ W,
             const float* __restrict__ bias, float* __restrict__ C) {
  __shared__ __bf16 As[2][128 * 64];
  __shared__ __bf16 Bs[2][128 * 64];
  const int bm = blockIdx.x, bn = blockIdx.y;
  const int tid = threadIdx.x, wave = tid >> 6, lane = tid & 63;
  const int wr = wave >> 1, wc = wave & 1;
  const int l15 = lane & 15, l4 = lane >> 4;
  const int rl = lane >> 3, c8 = lane & 7;
  f32x4 acc[4][4] = {};

#define FC_STAGE(bb, kt)                                                              \
  {                                                                                   \
    _Pragma("unroll")                                                                 \
    for (int i_ = 0; i_ < 4; ++i_) {                                                  \
      int row_ = wave * 32 + i_ * 8 + rl;                                             \
      int sw_ = (c8 ^ (row_ & 7)) << 3;                                               \
      gload_lds16(A + (size_t)(bm * 128 + row_) * 1024 + (kt) * 64 + sw_,             \
                  &As[bb][(wave * 32 + i_ * 8) * 64]);                                \
      gload_lds16(W + (size_t)(bn * 128 + row_) * 1024 + (kt) * 64 + sw_,             \
                  &Bs[bb][(wave * 32 + i_ * 8) * 64]);                                \
    }                                                                                 \
  }

  FC_STAGE(0, 0);
  FC_STAGE(1, 1);
  int cur = 0;
#pragma unroll 1
  for (int kt = 0; kt < 16; ++kt) {
    if (kt < 15) asm volatile("s_waitcnt vmcnt(8)" ::: "memory");
    else         asm volatile("s_waitcnt vmcnt(0)" ::: "memory");
    __builtin_amdgcn_s_barrier();
    __builtin_amdgcn_sched_barrier(0);
    bf16x8 af[4][2], bfr[4][2];
#pragma unroll
    for (int mi = 0; mi < 4; ++mi) {
      int row = wr * 64 + mi * 16 + l15;
#pragma unroll
      for (int k32 = 0; k32 < 2; ++k32)
        af[mi][k32] = *(const bf16x8*)(&As[cur][row * 64 + (((k32 * 4 + l4) ^ (row & 7)) << 3)]);
    }
#pragma unroll
    for (int ni = 0; ni < 4; ++ni) {
      int row = wc * 64 + ni * 16 + l15;
#pragma unroll
      for (int k32 = 0; k32 < 2; ++k32)
        bfr[ni][k32] = *(const bf16x8*)(&Bs[cur][row * 64 + (((k32 * 4 + l4) ^ (row & 7)) << 3)]);
    }
    asm volatile("s_waitcnt lgkmcnt(0)" ::: "memory");
    __builtin_amdgcn_sched_barrier(0);
    __builtin_amdgcn_s_barrier();
    __builtin_amdgcn_sched_barrier(0);
    if (kt < 14) FC_STAGE(cur, kt + 2);
    __builtin_amdgcn_s_setprio(1);
#pragma unroll
    for (int k32 = 0; k32 < 2; ++k32)
#pragma unroll
      for (int mi = 0; mi < 4; ++mi)
#pragma unroll
        for (int ni = 0; ni < 4; ++ni)
          acc[mi][ni] = MFMA16(af[mi][k32], bfr[ni][k32], acc[mi][ni]);
    __builtin_amdgcn_s_setprio(0);
    cur ^= 1;
  }
  const int r0 = l4 * 4, cl = l15;
#pragma unroll
  for (int ni = 0; ni < 4; ++ni) {
    int col = bn * 128 + wc * 64 + ni * 16 + cl;
    float bvv = bias[col];
#pragma unroll
    for (int mi = 0; mi < 4; ++mi) {
      int rowb = bm * 128 + wr * 64 + mi * 16 + r0;
#pragma unroll
      for (int r = 0; r < 4; ++r)
        C[(size_t)(rowb + r) * 1024 + col] = acc[mi][ni][r] + bvv;
    }
  }
#undef FC_STAGE
}

// ---------------- fused attention (r7-proven __syncthreads version) ----------------
__global__ __launch_bounds__(256)
void attn32(const __bf16* __restrict__ Qp, const __bf16* __restrict__ Kp,
            const __bf16* __restrict__ Vt, const unsigned int* __restrict__ mp,
            __bf16* __restrict__ O) {
  __shared__ __bf16 Ks[2][64 * 64];
  __shared__ __bf16 Vs[2][64 * 64];
  const int tid = threadIdx.x, wave = tid >> 6, lane = tid & 63;
  const int lo5 = lane & 31, hi = lane >> 5;
  const int bx = blockIdx.x;
  const int qt = bx & 7, h = (bx >> 3) & 15, b = bx >> 7;
  const int qrow = qt * 128 + wave * 32 + lo5;

  const int srow = tid >> 3;
  const int sgx = ((tid & 7) ^ (srow & 7)) << 3;

#define ATTN_STAGE(bb, kt)                                                            \
  {                                                                                   \
    _Pragma("unroll")                                                                 \
    for (int i = 0; i < 2; ++i) {                                                     \
      gload_lds16(Kp + (size_t)(b * 1024 + (kt) * 64 + i * 32 + srow) * 1024          \
                     + h * 64 + sgx,                                                  \
                  &Ks[bb][i * 2048 + wave * 512]);                                    \
      gload_lds16(Vt + (size_t)((b * 16 + h) * 64 + i * 32 + srow) * 1024             \
                     + (kt) * 64 + sgx,                                               \
                  &Vs[bb][i * 2048 + wave * 512]);                                    \
    }                                                                                 \
  }

  bf16x8 qf[4];
  const __bf16* qb = Qp + ((size_t)(b * 1024 + qrow)) * 1024 + h * 64 + hi * 8;
#pragma unroll
  for (int m = 0; m < 4; ++m) qf[m] = *(const bf16x8*)(qb + m * 16);

  bf16x8 onesf;
#pragma unroll
  for (int i = 0; i < 8; ++i) onesf[i] = (__bf16)1.0f;

  f32x16 oacc0 = {}, oacc1 = {}, oaccD = {};
  const uint2* mrow = ((const uint2*)mp) + ((size_t)(b * 1024 + qrow)) * 16;
  const int x = lo5 & 7;

  ATTN_STAGE(0, 0);
  uint2 mwc = mrow[0];
  __syncthreads();
  int buf = 0;
  for (int kt = 0; kt < 16; ++kt) {
    if (kt < 15) ATTN_STAGE(buf ^ 1, kt + 1);
    uint2 mwn = mwc;
    if (kt < 15) mwn = mrow[kt + 1];
#pragma unroll
    for (int sub = 0; sub < 2; ++sub) {
      f32x16 s = {};
#pragma unroll
      for (int m = 0; m < 4; ++m) {
        bf16x8 kf = *(const bf16x8*)(&Ks[buf][(sub * 32 + lo5) * 64 + (((2 * m + hi) ^ x) << 3)]);
        s = MFMA32(kf, qf[m], s);
      }
      unsigned w32 = sub == 0 ? mwc.x : mwc.y;
      unsigned nw = ~(w32 >> (hi * 4));
      float p[16];
#pragma unroll
      for (int r = 0; r < 16; ++r) {
        float e = __builtin_amdgcn_exp2f(s[r]);
        unsigned keep = (unsigned)__builtin_amdgcn_sbfe((int)nw, (unsigned)((r & 3) + 8 * (r >> 2)), 1u);
        p[r] = __uint_as_float(__float_as_uint(e) & keep);
      }
      unsigned own[8];
#pragma unroll
      for (int u = 0; u < 4; ++u) {
        own[2 * u]     = pack2(p[4 * u],     p[4 * u + 1]);
        own[2 * u + 1] = pack2(p[4 * u + 2], p[4 * u + 3]);
      }
#pragma unroll
      for (int sf = 0; sf < 2; ++sf) {
        unsigned a0 = own[4 * sf + 0], b0 = own[4 * sf + 2];
        unsigned a1 = own[4 * sf + 1], b1 = own[4 * sf + 3];
        asm volatile("v_permlane32_swap_b32 %0, %1" : "+v"(a0), "+v"(b0));
        asm volatile("v_permlane32_swap_b32 %0, %1" : "+v"(a1), "+v"(b1));
        bf16x8 pa = mkfrag(a0, a1, b0, b1);
        int g = ((sub * 4 + sf * 2 + hi) ^ x) << 3;
        bf16x8 vf0 = *(const bf16x8*)(&Vs[buf][lo5 * 64 + g]);
        bf16x8 vf1 = *(const bf16x8*)(&Vs[buf][(lo5 + 32) * 64 + g]);
        oacc0 = MFMA32(pa, vf0, oacc0);
        oacc1 = MFMA32(pa, vf1, oacc1);
        oaccD = MFMA32(pa, onesf, oaccD);
      }
    }
    __syncthreads();
    buf ^= 1;
    mwc = mwn;
  }

  const size_t orow0 = (size_t)(b * 1024 + qt * 128 + wave * 32);
#pragma unroll
  for (int r = 0; r < 16; ++r) {
    int cr = (r & 3) + 8 * (r >> 2) + 4 * hi;
    float iv = __builtin_amdgcn_rcpf(oaccD[r]);
    __bf16* op = O + (orow0 + cr) * 1024 + h * 64 + lo5;
    op[0]  = (__bf16)(oacc0[r] * iv);
    op[32] = (__bf16)(oacc1[r] * iv);
  }
#undef ATTN_STAGE
}

// ---------------- launch ----------------
extern "C" void kernel_launch(void* const* d_in, const int* in_sizes, int n_in,
                              void* d_out, int out_size, void* d_ws, size_t ws_size,
                              hipStream_t stream) {
  const float* query = (const float*)d_in[0];
  const float* key   = (const float*)d_in[1];
  const float* value = (const float*)d_in[2];
  const void*  mask  = d_in[3];
  const float* wq_w  = (const float*)d_in[4];
  const float* wq_b  = (const float*)d_in[5];
  const float* wk_w  = (const float*)d_in[6];
  const float* wk_b  = (const float*)d_in[7];
  const float* wv_w  = (const float*)d_in[8];
  const float* wv_b  = (const float*)d_in[9];
  const float* fc_w  = (const float*)d_in[10];
  const float* fc_b  = (const float*)d_in[11];

  char* ws = (char*)d_ws;
  __bf16* qb  = (__bf16*)ws;
  __bf16* kb  = qb  + 4194304;
  __bf16* vb  = kb  + 4194304;
  __bf16* wqb = vb  + 4194304;
  __bf16* wkb = wqb + 1048576;
  __bf16* wvb = wkb + 1048576;
  __bf16* fcb = wvb + 1048576;
  __bf16* Qp  = fcb + 1048576;
  __bf16* Kp  = Qp  + 4194304;
  __bf16* Vt  = Kp  + 4194304;        // V proj, per-head transposed [B,H,64,S]
  __bf16* Ob  = Vt  + 4194304;
  unsigned int* mpk = (unsigned int*)(Ob + 4194304);
  int* flag = (int*)(mpk + 131072);

  detect_mask<<<1, 256, 0, stream>>>((const unsigned char*)mask, flag);
  pack_mask<<<16384, 256, 0, stream>>>(mask, flag, mpk);
  cvt_all<<<16384, 256, 0, stream>>>(query, key, value, wq_w, wk_w, wv_w, fc_w,
                                     qb, kb, vb, wqb, wkb, wvb, fcb);
  dim3 g1(32, 24);
  gemm_qkv2<<<g1, 256, 0, stream>>>(qb, kb, vb, wqb, wkb, wvb, wq_b, wk_b, wv_b, Qp, Kp, Vt);
  attn32<<<512, 256, 0, stream>>>(Qp, Kp, Vt, mpk, Ob);
  dim3 g2(32, 8);
  gemm_fc<<<g2, 256, 0, stream>>>(Ob, fcb, fc_b, (float*)d_out);
}